// Round 9
// baseline (196.019 us; speedup 1.0000x reference)
//
#include <hip/hip_runtime.h>
#include <math.h>

#define N_PTS 16384
#define D_DIM 128
#define C_CLS 10
#define K_MIX 16
#define HB    64                      // histogram/scatter blocks (256 pts each)
#define GRID3 256                     // main blocks: 64 sorted points each

constexpr float EPSF   = 1.1920928955078125e-07f;  // np.finfo(float32).eps
constexpr float LOG2PI = 1.8378770664093453f;
constexpr float LN2F   = 0.6931471805599453f;

__device__ __forceinline__ float softplusf(float x) {
    if (x > 20.f)  return x;
    if (x < -20.f) return expf(x);
    return log1pf(expf(x));
}
__device__ __forceinline__ float ndtrf(float x) {
    return 0.5f * erfcf(-x * 0.70710678118654752440f);
}

// ---------------------------------------------------------------------------
// K1 (round-2 proven, verbatim): blocks [0,160): per-(c,k) params ->
// abT(float2 {is^2, 2 mu is^2})[c][d][k], loT/upT[c][d][k], Ack[c*K+k].
// blocks [160,224): per-256-pt class histogram -> blockCnt[h][c].
// ---------------------------------------------------------------------------
__global__ __launch_bounds__(256) void k_prep(
    const float* __restrict__ mu, const float* __restrict__ lower,
    const float* __restrict__ upper, const float* __restrict__ sigma,
    const int* __restrict__ y,
    float2* __restrict__ abT, float* __restrict__ loT, float* __restrict__ upT,
    float* __restrict__ Ack, int* __restrict__ blockCnt) {
    int b = blockIdx.x, t = threadIdx.x;
    if (b < C_CLS * K_MIX) {
        int c = b / K_MIX, k = b % K_MIX;
        __shared__ float rs0[256], rs1[256], rp[256];
        float logsc = 0.f, mu2 = 0.f, zz = 1.f;
        if (t < D_DIM) {
            int gi = b * D_DIM + t;
            float m = mu[gi], lo = lower[gi], up = upper[gi], sg = sigma[gi];
            float sc = EPSF + softplusf(sg);
            float is = 1.f / sc;
            int ti = (c * D_DIM + t) * K_MIX + k;
            abT[ti] = make_float2(is * is, 2.f * m * is * is);
            loT[ti] = lo; upT[ti] = up;
            logsc = logf(sc);
            mu2   = m * m * is * is;
            zz    = ndtrf((up - m) * is) - ndtrf((lo - m) * is);
        }
        rs0[t] = logsc; rs1[t] = mu2; rp[t] = zz;
        __syncthreads();
        for (int off = 128; off > 0; off >>= 1) {
            if (t < off) { rs0[t] += rs0[t+off]; rs1[t] += rs1[t+off]; rp[t] *= rp[t+off]; }
            __syncthreads();
        }
        if (t == 0) {
            float log_norm = logf(rp[0] + EPSF);
            Ack[b] = -log_norm - rs0[0] - 0.5f * (float)D_DIM * LOG2PI - 0.5f * rs1[0];
        }
    } else {
        int h = b - C_CLS * K_MIX;
        __shared__ int hist[C_CLS];
        if (t < C_CLS) hist[t] = 0;
        __syncthreads();
        int c = y[h * 256 + t];
        int lane = t & 63;
        for (int cc = 0; cc < C_CLS; ++cc) {
            unsigned long long m = __ballot(c == cc);
            if (lane == 0 && m) atomicAdd(&hist[cc], __popcll(m));
        }
        __syncthreads();
        if (t < C_CLS) blockCnt[h * C_CLS + t] = hist[t];
    }
}

// ---------------------------------------------------------------------------
// K2 (round-2 proven, verbatim + done-counter zeroing): stable counting-sort
// scatter -> idxSorted; block 0 also writes classOff / invden / const_ck.
// ---------------------------------------------------------------------------
__global__ __launch_bounds__(256) void k_scatter(
    const int* __restrict__ y, const int* __restrict__ blockCnt,
    const float* __restrict__ logits, const float* __restrict__ Ack,
    int* __restrict__ idxSorted, int* __restrict__ classOff,
    float* __restrict__ invden, float* __restrict__ const_ck,
    int* __restrict__ done) {
    __shared__ int sCnt[HB * C_CLS];
    __shared__ int sOff[C_CLS + 1];
    __shared__ int sMyOff[C_CLS];
    __shared__ int wcnt[4][C_CLS];
    __shared__ int wbase[4][C_CLS];
    int h = blockIdx.x, t = threadIdx.x;
    if (h == 0 && t == 0) *done = 0;            // init last-block counter
    for (int i = t; i < HB * C_CLS; i += 256) sCnt[i] = blockCnt[i];
    __syncthreads();
    if (t == 0) {
        int acc = 0;
        for (int c = 0; c < C_CLS; ++c) {
            sOff[c] = acc;
            int s = 0;
            for (int hh = 0; hh < HB; ++hh) s += sCnt[hh * C_CLS + c];
            acc += s;
        }
        sOff[C_CLS] = acc;
    }
    __syncthreads();
    if (t < C_CLS) {
        int s = sOff[t];
        for (int hh = 0; hh < h; ++hh) s += sCnt[hh * C_CLS + t];
        sMyOff[t] = s;
    }
    __syncthreads();
    int n = h * 256 + t;
    int c = y[n];
    int w = t >> 6, lane = t & 63;
    int rank = 0;
    for (int cc = 0; cc < C_CLS; ++cc) {
        unsigned long long m = __ballot(c == cc);
        if (c == cc) rank = __popcll(m & ((1ull << lane) - 1ull));
        if (lane == 0) wcnt[w][cc] = __popcll(m);
    }
    __syncthreads();
    if (t < 4 * C_CLS) {
        int ww = t / C_CLS, cc = t % C_CLS;
        int s = sMyOff[cc];
        for (int w2 = 0; w2 < ww; ++w2) s += wcnt[w2][cc];
        wbase[ww][cc] = s;
    }
    __syncthreads();
    idxSorted[wbase[w][c] + rank] = n;

    if (h == 0) {
        __shared__ float lse[C_CLS];
        if (t < C_CLS) {
            float mx = -1e30f;
            for (int k = 0; k < K_MIX; ++k) mx = fmaxf(mx, logits[t * K_MIX + k]);
            float se = 0.f;
            for (int k = 0; k < K_MIX; ++k) se += expf(logits[t * K_MIX + k] - mx);
            lse[t] = mx + logf(se);
            int cnt = sOff[t + 1] - sOff[t];
            invden[t] = (cnt > 0) ? 1.f / ((float)cnt * (float)K_MIX) : 0.f;
        }
        if (t < C_CLS + 1) classOff[t] = sOff[t];
        __syncthreads();
        if (t < C_CLS * K_MIX) const_ck[t] = logits[t] - lse[t / K_MIX] + Ack[t];
    }
}

// ---------------------------------------------------------------------------
// K3: main. 256 blocks x 1024 threads (16 waves -> 4 waves/SIMD, which forces
// VGPR <= 128: the round-8 fix). Thread = (nl, k) over 64 sorted points per
// block. X staged to LDS [64][132] (round-1 proven); params streamed from L2
// (class-uniform waves -> one 128B line per (wave,d)). k-shuffle reduce,
// 64-wide wave-0 block reduce, 256 done-atomics + last-block final reduce.
// ---------------------------------------------------------------------------
__global__ __launch_bounds__(1024) void k_main(
    const float* __restrict__ X, const int* __restrict__ y,
    const float* __restrict__ resp,
    const float2* __restrict__ abT, const float* __restrict__ loT,
    const float* __restrict__ upT, const float* __restrict__ const_ck,
    const float* __restrict__ invden, const int* __restrict__ idxSorted,
    const float* __restrict__ etap,
    float* __restrict__ partials, int* __restrict__ done,
    float* __restrict__ out) {
    const int b = blockIdx.x, t = threadIdx.x;
    const int k = t & 15, nl = t >> 4;          // nl in [0,64)
    __shared__ float xs[64][132];               // ~33.8 KB
    __shared__ int   sIdx[64];
    __shared__ int   sC[64];
    __shared__ float sums[64];
    __shared__ int   sLast;

    if (t < 64) {
        int n = idxSorted[b * 64 + t];
        sIdx[t] = n;
        sC[t]   = y[n];
    }
    __syncthreads();
    // stage 64 rows (8192 floats = 2048 float4): thread t does slots t, t+1024
    #pragma unroll
    for (int i = 0; i < 2; ++i) {
        int jj = t + i * 1024;
        int r  = jj >> 5, c4 = jj & 31;
        float4 v = *reinterpret_cast<const float4*>(
            X + (size_t)sIdx[r] * D_DIM + c4 * 4);
        xs[r][c4 * 4 + 0] = v.x; xs[r][c4 * 4 + 1] = v.y;
        xs[r][c4 * 4 + 2] = v.z; xs[r][c4 * 4 + 3] = v.w;
    }
    __syncthreads();

    const int n = sIdx[nl];
    const int c = sC[nl];
    const float eta = etap[0];
    const float2* ap = abT + (size_t)c * (D_DIM * K_MIX) + k;

    float acc0 = 0.f, acc1 = 0.f;
    for (int d0 = 0; d0 < D_DIM; d0 += 8) {
        float2 pv[8];
        #pragma unroll
        for (int q = 0; q < 8; ++q) pv[q] = ap[(size_t)(d0 + q) * K_MIX];
        #pragma unroll
        for (int q = 0; q < 8; q += 2) {
            float x0 = xs[nl][d0 + q], x1 = xs[nl][d0 + q + 1];
            acc0 = fmaf(x0, fmaf(pv[q].x,   x0, -pv[q].y),   acc0);
            acc1 = fmaf(x1, fmaf(pv[q+1].x, x1, -pv[q+1].y), acc1);
        }
    }
    float acc = acc0 + acc1;

    float lp;
    if (eta == 0.f) {
        lp = -2.f * (float)D_DIM * LN2F;
    } else {
        lp = 0.f;
        const float* lo = loT + (size_t)c * (D_DIM * K_MIX) + k;
        const float* up = upT + (size_t)c * (D_DIM * K_MIX) + k;
        for (int d0 = 0; d0 < D_DIM; d0 += 8) {
            float lv[8], uv[8];
            #pragma unroll
            for (int q = 0; q < 8; ++q) lv[q] = lo[(size_t)(d0 + q) * K_MIX];
            #pragma unroll
            for (int q = 0; q < 8; ++q) uv[q] = up[(size_t)(d0 + q) * K_MIX];
            #pragma unroll
            for (int q = 0; q < 8; ++q) {
                float x = xs[nl][d0 + q];
                lp -= softplusf(-eta * (x - lv[q]))
                    + softplusf(-eta * (uv[q] - x));
            }
        }
    }

    float r_ = resp[((size_t)c * N_PTS + n) * K_MIX + k];
    float v  = r_ * (const_ck[c * K_MIX + k] + lp - 0.5f * acc) * invden[c];

    // sum over the 16 k-lanes of this n (fixed-order tree; round-1 proven)
    v += __shfl_xor(v, 1);
    v += __shfl_xor(v, 2);
    v += __shfl_xor(v, 4);
    v += __shfl_xor(v, 8);
    if (k == 0) sums[nl] = v;
    __syncthreads();
    if (t < 64) {
        float s = sums[t];
        #pragma unroll
        for (int o = 1; o < 64; o <<= 1) s += __shfl_xor(s, o);
        if (t == 0) {
            partials[b] = s;
            __threadfence();
            int prev = __hip_atomic_fetch_add(done, 1, __ATOMIC_ACQ_REL,
                                              __HIP_MEMORY_SCOPE_AGENT);
            sLast = (prev == GRID3 - 1);
        }
    }
    __syncthreads();

    if (sLast) {
        __threadfence();
        if (t < 64) {
            float s = partials[t] + partials[t + 64]
                    + partials[t + 128] + partials[t + 192];
            #pragma unroll
            for (int o = 1; o < 64; o <<= 1) s += __shfl_xor(s, o);
            if (t == 0) out[0] = -s;
        }
    }
}

// ---------------------------------------------------------------------------
extern "C" void kernel_launch(void* const* d_in, const int* in_sizes, int n_in,
                              void* d_out, int out_size, void* d_ws, size_t ws_size,
                              hipStream_t stream) {
    const float* X      = (const float*)d_in[0];
    const int*   y      = (const int*)  d_in[1];
    const float* resp   = (const float*)d_in[2];
    const float* mu     = (const float*)d_in[3];
    const float* lower  = (const float*)d_in[4];
    const float* upper  = (const float*)d_in[5];
    const float* sigma  = (const float*)d_in[6];
    const float* logits = (const float*)d_in[7];
    const float* eta    = (const float*)d_in[8];
    float* out = (float*)d_out;

    char* ws = (char*)d_ws;
    size_t off = 256;                 // first 256 B: done counter
    auto alloc = [&](size_t bytes) {
        void* p = ws + off;
        off += (bytes + 255) & ~size_t(255);
        return p;
    };
    const size_t PE = (size_t)C_CLS * D_DIM * K_MIX;
    int*    done     = (int*)ws;
    float2* abT      = (float2*)alloc(PE * sizeof(float2));
    float*  loT      = (float*) alloc(PE * sizeof(float));
    float*  upT      = (float*) alloc(PE * sizeof(float));
    float*  Ack      = (float*) alloc(C_CLS * K_MIX * sizeof(float));
    float*  const_ck = (float*) alloc(C_CLS * K_MIX * sizeof(float));
    int*    blockCnt = (int*)   alloc(HB * C_CLS * sizeof(int));
    int*    idxSorted= (int*)   alloc(N_PTS * sizeof(int));
    int*    classOff = (int*)   alloc((C_CLS + 1) * sizeof(int));
    float*  invden   = (float*) alloc(C_CLS * sizeof(float));
    float*  partials = (float*) alloc(GRID3 * sizeof(float));

    k_prep<<<C_CLS * K_MIX + HB, 256, 0, stream>>>(
        mu, lower, upper, sigma, y, abT, loT, upT, Ack, blockCnt);
    k_scatter<<<HB, 256, 0, stream>>>(
        y, blockCnt, logits, Ack, idxSorted, classOff, invden, const_ck, done);
    k_main<<<GRID3, 1024, 0, stream>>>(
        X, y, resp, abT, loT, upT, const_ck, invden, idxSorted, eta,
        partials, done, out);
}

// Round 10
// 59.929 us; speedup vs baseline: 3.2709x; 3.2709x over previous
//
#include <hip/hip_runtime.h>
#include <math.h>

#define N_PTS 16384
#define D_DIM 128
#define C_CLS 10
#define K_MIX 16
#define HB    64                      // histogram/scatter blocks (256 pts each)
#define BPC   103                     // main blocks per class
#define GRID3 (C_CLS * BPC)           // 1030 main blocks (~4/CU)

constexpr float EPSF   = 1.1920928955078125e-07f;  // np.finfo(float32).eps
constexpr float LOG2PI = 1.8378770664093453f;
constexpr float LN2F   = 0.6931471805599453f;

__device__ __forceinline__ float softplusf(float x) {
    if (x > 20.f)  return x;
    if (x < -20.f) return expf(x);
    return log1pf(expf(x));
}
__device__ __forceinline__ float ndtrf(float x) {
    return 0.5f * erfcf(-x * 0.70710678118654752440f);
}

// ---------------------------------------------------------------------------
// K1 (round-2 proven, verbatim): blocks [0,160): per-(c,k) params ->
// abT(float2 {is^2, 2 mu is^2})[c][d][k], loT/upT[c][d][k], Ack[c*K+k].
// blocks [160,224): per-256-pt class histogram -> blockCnt[h][c].
// ---------------------------------------------------------------------------
__global__ __launch_bounds__(256) void k_prep(
    const float* __restrict__ mu, const float* __restrict__ lower,
    const float* __restrict__ upper, const float* __restrict__ sigma,
    const int* __restrict__ y,
    float2* __restrict__ abT, float* __restrict__ loT, float* __restrict__ upT,
    float* __restrict__ Ack, int* __restrict__ blockCnt) {
    int b = blockIdx.x, t = threadIdx.x;
    if (b < C_CLS * K_MIX) {
        int c = b / K_MIX, k = b % K_MIX;
        __shared__ float rs0[256], rs1[256], rp[256];
        float logsc = 0.f, mu2 = 0.f, zz = 1.f;
        if (t < D_DIM) {
            int gi = b * D_DIM + t;
            float m = mu[gi], lo = lower[gi], up = upper[gi], sg = sigma[gi];
            float sc = EPSF + softplusf(sg);
            float is = 1.f / sc;
            int ti = (c * D_DIM + t) * K_MIX + k;
            abT[ti] = make_float2(is * is, 2.f * m * is * is);
            loT[ti] = lo; upT[ti] = up;
            logsc = logf(sc);
            mu2   = m * m * is * is;
            zz    = ndtrf((up - m) * is) - ndtrf((lo - m) * is);
        }
        rs0[t] = logsc; rs1[t] = mu2; rp[t] = zz;
        __syncthreads();
        for (int off = 128; off > 0; off >>= 1) {
            if (t < off) { rs0[t] += rs0[t+off]; rs1[t] += rs1[t+off]; rp[t] *= rp[t+off]; }
            __syncthreads();
        }
        if (t == 0) {
            float log_norm = logf(rp[0] + EPSF);
            Ack[b] = -log_norm - rs0[0] - 0.5f * (float)D_DIM * LOG2PI - 0.5f * rs1[0];
        }
    } else {
        int h = b - C_CLS * K_MIX;
        __shared__ int hist[C_CLS];
        if (t < C_CLS) hist[t] = 0;
        __syncthreads();
        int c = y[h * 256 + t];
        int lane = t & 63;
        for (int cc = 0; cc < C_CLS; ++cc) {
            unsigned long long m = __ballot(c == cc);
            if (lane == 0 && m) atomicAdd(&hist[cc], __popcll(m));
        }
        __syncthreads();
        if (t < C_CLS) blockCnt[h * C_CLS + t] = hist[t];
    }
}

// ---------------------------------------------------------------------------
// K2 (round-2 proven, verbatim + done-counter zeroing): stable counting-sort
// scatter -> idxSorted; block 0 also writes classOff / invden / const_ck.
// ---------------------------------------------------------------------------
__global__ __launch_bounds__(256) void k_scatter(
    const int* __restrict__ y, const int* __restrict__ blockCnt,
    const float* __restrict__ logits, const float* __restrict__ Ack,
    int* __restrict__ idxSorted, int* __restrict__ classOff,
    float* __restrict__ invden, float* __restrict__ const_ck,
    int* __restrict__ done) {
    __shared__ int sCnt[HB * C_CLS];
    __shared__ int sOff[C_CLS + 1];
    __shared__ int sMyOff[C_CLS];
    __shared__ int wcnt[4][C_CLS];
    __shared__ int wbase[4][C_CLS];
    int h = blockIdx.x, t = threadIdx.x;
    if (h == 0 && t == 0) *done = 0;            // init last-block counter
    for (int i = t; i < HB * C_CLS; i += 256) sCnt[i] = blockCnt[i];
    __syncthreads();
    if (t == 0) {
        int acc = 0;
        for (int c = 0; c < C_CLS; ++c) {
            sOff[c] = acc;
            int s = 0;
            for (int hh = 0; hh < HB; ++hh) s += sCnt[hh * C_CLS + c];
            acc += s;
        }
        sOff[C_CLS] = acc;
    }
    __syncthreads();
    if (t < C_CLS) {
        int s = sOff[t];
        for (int hh = 0; hh < h; ++hh) s += sCnt[hh * C_CLS + t];
        sMyOff[t] = s;
    }
    __syncthreads();
    int n = h * 256 + t;
    int c = y[n];
    int w = t >> 6, lane = t & 63;
    int rank = 0;
    for (int cc = 0; cc < C_CLS; ++cc) {
        unsigned long long m = __ballot(c == cc);
        if (c == cc) rank = __popcll(m & ((1ull << lane) - 1ull));
        if (lane == 0) wcnt[w][cc] = __popcll(m);
    }
    __syncthreads();
    if (t < 4 * C_CLS) {
        int ww = t / C_CLS, cc = t % C_CLS;
        int s = sMyOff[cc];
        for (int w2 = 0; w2 < ww; ++w2) s += wcnt[w2][cc];
        wbase[ww][cc] = s;
    }
    __syncthreads();
    idxSorted[wbase[w][c] + rank] = n;

    if (h == 0) {
        __shared__ float lse[C_CLS];
        if (t < C_CLS) {
            float mx = -1e30f;
            for (int k = 0; k < K_MIX; ++k) mx = fmaxf(mx, logits[t * K_MIX + k]);
            float se = 0.f;
            for (int k = 0; k < K_MIX; ++k) se += expf(logits[t * K_MIX + k] - mx);
            lse[t] = mx + logf(se);
            int cnt = sOff[t + 1] - sOff[t];
            invden[t] = (cnt > 0) ? 1.f / ((float)cnt * (float)K_MIX) : 0.f;
        }
        if (t < C_CLS + 1) classOff[t] = sOff[t];
        __syncthreads();
        if (t < C_CLS * K_MIX) const_ck[t] = logits[t] - lse[t / K_MIX] + Ack[t];
    }
}

// ---------------------------------------------------------------------------
// K3: main. 1030 class-striped blocks (~4/CU) x 256 threads,
// __launch_bounds__(256,4) -> VGPR<=128, 16 waves/CU. Lane = (k, dc);
// a_[32]/b_[32] params in registers (R6-proven); 16-point X batch in LDS with
// stride-36 disjoint-bank segments (R7-proven); 4 points/wave, zero per-point
// shuffles (ck/4 trick); one end butterfly; initialized last-block reduce.
// ---------------------------------------------------------------------------
__global__ __launch_bounds__(256, 4) void k_main(
    const float* __restrict__ X, const float* __restrict__ resp,
    const float2* __restrict__ abT, const float* __restrict__ loT,
    const float* __restrict__ upT, const float* __restrict__ const_ck,
    const int* __restrict__ classOff, const float* __restrict__ invden,
    const int* __restrict__ idxSorted, const float* __restrict__ etap,
    float* __restrict__ partials, int* __restrict__ done,
    float* __restrict__ out) {
    const int b = blockIdx.x, t = threadIdx.x;
    const int w = t >> 6, lane = t & 63;
    const int k = lane & 15, dc = lane >> 4;
    const int d0 = dc * 32;
    const int c = b / BPC, j = b % BPC;

    __shared__ float xs[16][144];     // 4 segs of 32 @ stride 36 -> banks 4dc..4dc+3
    __shared__ int   sIdx[16];
    __shared__ float sW[4];
    __shared__ int   sLast;

    // register params from L2-resident abT[c][d][k]
    float a_[32], b_[32];
    {
        const float2* ap = abT + ((size_t)c * D_DIM + d0) * K_MIX + k;
        #pragma unroll
        for (int i = 0; i < 32; ++i) { float2 v = ap[i * K_MIX]; a_[i] = v.x; b_[i] = v.y; }
    }
    const float eta = etap[0];
    const float lpconst = -2.f * (float)D_DIM * LN2F;
    const float ck4 = 0.25f * (const_ck[c * K_MIX + k] + (eta == 0.f ? lpconst : 0.f));
    const float inv = invden[c];
    const int   off = classOff[c];
    const int   cnt = classOff[c + 1] - off;

    float wsum = 0.f;
    for (int base = j * 16; base < cnt; base += BPC * 16) {
        int bn = cnt - base; if (bn > 16) bn = 16;
        __syncthreads();                     // guard xs/sIdx reuse (rare 2nd batch)
        if (t < 16) sIdx[t] = idxSorted[off + base + ((t < bn) ? t : 0)];
        __syncthreads();
        // stage bn rows: 32 consecutive lanes write one row (coalesced 512B)
        {
            int row = t >> 5, s = t & 31;    // rows 0..7
            if (row < bn) {
                float4 v = *reinterpret_cast<const float4*>(
                    X + (size_t)sIdx[row] * D_DIM + s * 4);
                *reinterpret_cast<float4*>(&xs[row][(s >> 3) * 36 + (s & 7) * 4]) = v;
            }
            row += 8;
            if (row < bn) {
                float4 v = *reinterpret_cast<const float4*>(
                    X + (size_t)sIdx[row] * D_DIM + s * 4);
                *reinterpret_cast<float4*>(&xs[row][(s >> 3) * 36 + (s & 7) * 4]) = v;
            }
        }
        __syncthreads();
        // wave w processes points w, w+4, w+8, w+12 (wave-uniform guard)
        #pragma unroll
        for (int pi = 0; pi < 4; ++pi) {
            int pt = w + pi * 4;
            if (pt >= bn) break;
            int n = sIdx[pt];
            float r_ = resp[((size_t)c * N_PTS + n) * K_MIX + k];
            const float* xrow = &xs[pt][dc * 36];
            float acc0 = 0.f, acc1 = 0.f;
            #pragma unroll
            for (int q = 0; q < 8; ++q) {
                float4 xv = *reinterpret_cast<const float4*>(xrow + q * 4);
                acc0 = fmaf(xv.x, fmaf(a_[q*4+0], xv.x, -b_[q*4+0]), acc0);
                acc1 = fmaf(xv.y, fmaf(a_[q*4+1], xv.y, -b_[q*4+1]), acc1);
                acc0 = fmaf(xv.z, fmaf(a_[q*4+2], xv.z, -b_[q*4+2]), acc0);
                acc1 = fmaf(xv.w, fmaf(a_[q*4+3], xv.w, -b_[q*4+3]), acc1);
            }
            float acc = acc0 + acc1;
            if (eta == 0.f) {
                wsum = fmaf(r_, fmaf(-0.5f, acc, ck4), wsum);
            } else {
                float lpp = 0.f;
                const float* lo = loT + ((size_t)c * D_DIM + d0) * K_MIX + k;
                const float* up = upT + ((size_t)c * D_DIM + d0) * K_MIX + k;
                #pragma unroll 8
                for (int q = 0; q < 32; ++q) {
                    float x = xrow[(q >> 2) * 4 + (q & 3)];
                    lpp -= softplusf(-eta * (x - lo[q * K_MIX]))
                         + softplusf(-eta * (up[q * K_MIX] - x));
                }
                wsum = fmaf(r_, fmaf(-0.5f, acc, ck4 + lpp), wsum);
            }
        }
    }
    wsum *= inv;

    // single fixed-order butterfly over the wave, then block combine
    #pragma unroll
    for (int o = 1; o < 64; o <<= 1) wsum += __shfl_xor(wsum, o);
    if (lane == 0) sW[w] = wsum;
    __syncthreads();
    if (t == 0) {
        partials[b] = sW[0] + sW[1] + sW[2] + sW[3];
        __threadfence();
        int prev = __hip_atomic_fetch_add(done, 1, __ATOMIC_ACQ_REL,
                                          __HIP_MEMORY_SCOPE_AGENT);
        sLast = (prev == GRID3 - 1);
    }
    __syncthreads();

    if (sLast) {
        __threadfence();
        __shared__ float red[256];
        float s = 0.f;
        for (int i = t; i < GRID3; i += 256) s += partials[i];
        red[t] = s;
        __syncthreads();
        for (int o = 128; o > 0; o >>= 1) {
            if (t < o) red[t] += red[t + o];
            __syncthreads();
        }
        if (t == 0) out[0] = -red[0];
    }
}

// ---------------------------------------------------------------------------
extern "C" void kernel_launch(void* const* d_in, const int* in_sizes, int n_in,
                              void* d_out, int out_size, void* d_ws, size_t ws_size,
                              hipStream_t stream) {
    const float* X      = (const float*)d_in[0];
    const int*   y      = (const int*)  d_in[1];
    const float* resp   = (const float*)d_in[2];
    const float* mu     = (const float*)d_in[3];
    const float* lower  = (const float*)d_in[4];
    const float* upper  = (const float*)d_in[5];
    const float* sigma  = (const float*)d_in[6];
    const float* logits = (const float*)d_in[7];
    const float* eta    = (const float*)d_in[8];
    float* out = (float*)d_out;

    char* ws = (char*)d_ws;
    size_t off = 256;                 // first 256 B: done counter
    auto alloc = [&](size_t bytes) {
        void* p = ws + off;
        off += (bytes + 255) & ~size_t(255);
        return p;
    };
    const size_t PE = (size_t)C_CLS * D_DIM * K_MIX;
    int*    done     = (int*)ws;
    float2* abT      = (float2*)alloc(PE * sizeof(float2));
    float*  loT      = (float*) alloc(PE * sizeof(float));
    float*  upT      = (float*) alloc(PE * sizeof(float));
    float*  Ack      = (float*) alloc(C_CLS * K_MIX * sizeof(float));
    float*  const_ck = (float*) alloc(C_CLS * K_MIX * sizeof(float));
    int*    blockCnt = (int*)   alloc(HB * C_CLS * sizeof(int));
    int*    idxSorted= (int*)   alloc(N_PTS * sizeof(int));
    int*    classOff = (int*)   alloc((C_CLS + 1) * sizeof(int));
    float*  invden   = (float*) alloc(C_CLS * sizeof(float));
    float*  partials = (float*) alloc(GRID3 * sizeof(float));

    k_prep<<<C_CLS * K_MIX + HB, 256, 0, stream>>>(
        mu, lower, upper, sigma, y, abT, loT, upT, Ack, blockCnt);
    k_scatter<<<HB, 256, 0, stream>>>(
        y, blockCnt, logits, Ack, idxSorted, classOff, invden, const_ck, done);
    k_main<<<GRID3, 256, 0, stream>>>(
        X, resp, abT, loT, upT, const_ck, classOff, invden, idxSorted, eta,
        partials, done, out);
}